// Round 9
// baseline (410.744 us; speedup 1.0000x reference)
//
#include <hip/hip_runtime.h>

#define EPS_F 1e-5f

typedef __attribute__((ext_vector_type(8))) short short8;
typedef __attribute__((ext_vector_type(4))) float f32x4;
typedef __attribute__((ext_vector_type(4))) unsigned short ushort4v;
typedef __attribute__((address_space(1))) void gvoid;
typedef __attribute__((address_space(3))) void svoid;

__device__ __forceinline__ float bf2f(unsigned short u){
    union { unsigned int i; float f; } v; v.i = ((unsigned int)u) << 16; return v.f;
}
__device__ __forceinline__ unsigned short f2bf(float f){
    union { float f; unsigned int i; } v; v.f = f;
    unsigned int r = v.i + 0x7FFFu + ((v.i >> 16) & 1u);
    return (unsigned short)(r >> 16);
}
__device__ __forceinline__ void blockbar() {
    __builtin_amdgcn_sched_barrier(0);
    __builtin_amdgcn_s_barrier();
    __builtin_amdgcn_sched_barrier(0);
}

// ---------------------------------------------------------------------------
// bf16 MFMA GEMM v2: C[m][n] = sum_k A[m][k] * Act[n][k]  (both K-contig)
//  - A (weights, L2-hot) streamed global->reg, prefetched 1 K-step ahead
//  - B (activations) double-buffered in LDS via global_load_lds, staged
//    2 K-steps ahead; main loop waits vmcnt(4) (counted, never 0) with raw
//    s_barrier (no compiler drain).  LDS = 2 x 16 KB.
// Flying set at the wait point: B(k+1)[4, oldest] + A(k+1)[8] + B(k+2)[4]
//   -> vmcnt(4) retires exactly B(k+1)+A(k+1), leaves B(k+2) in flight.
// Tile 128x128, BK=64, 4 waves (2x2), 4x4 MFMA frags, KS = K/64.
// EPI 0: +bias              -> outT NHWC bf16            (qkv)
// EPI 1: +bias +resid(NCHW) -> outT NHWC bf16 + outF f32 (proj -> x1)
// EPI 2: BN+SiLU            -> outT NHWC bf16            (mlp1)
// EPI 3: BN+resid(NCHW)     -> outF f32 NCHW             (mlp2 -> out)
// ---------------------------------------------------------------------------
template<int EPI, int KS>
__global__ __launch_bounds__(256, 3)
void ga_k(const short* __restrict__ A, const short* __restrict__ Bt,
          const int M,
          const float* __restrict__ p0, const float* __restrict__ p1,
          const float* __restrict__ p2, const float* __restrict__ p3,
          const float* __restrict__ resid,
          short* __restrict__ outT, float* __restrict__ outF)
{
    const int N = 6400;
    const int K = KS * 64;
    __shared__ short lsB[2][128 * 64];   // 2 x 16 KB

    const int id = blockIdx.x;
    const int b  = id & 7;               // XCD swizzle: batch -> XCD
    const int rr = id >> 3;
    const int n0 = (rr % 50) * 128;
    const int m0 = (rr / 50) * 128;
    const int t  = threadIdx.x;
    const int l  = t & 63;
    const int w  = t >> 6;
    const int wr = w >> 1, wc = w & 1;

    const short* Bb = Bt + (size_t)b * N * K;
    const int rsub = l >> 3;             // 0..7 row in 8-row stage group
    const int csub = l & 7;              // 0..7 16B chunk in 128B row

    // stage B K-step k into LDS buffer bufi (pre-swizzled global source)
    auto stageB = [&](int k, int bufi) {
        #pragma unroll
        for (int q = 0; q < 4; ++q) {
            const int row = (w * 4 + q) * 8 + rsub;
            const int cs  = csub ^ (row & 7);
            const short* gb = Bb + (size_t)(n0 + row) * K + k * 64 + (cs << 3);
            __builtin_amdgcn_global_load_lds((gvoid*)gb,
                (svoid*)(&lsB[bufi][(w * 4 + q) * 512]), 16, 0, 0);
        }
    };

    // A fragment base: row = m0 + wr*64 + mi*16 + (l&15), k-chunk (l>>4)*8
    const short* Aw = A + (size_t)(m0 + wr * 64 + (l & 15)) * K + ((l >> 4) << 3);
    short8 areg[2][2][4];
    auto loadA = [&](int k, int pb) {
        #pragma unroll
        for (int ks = 0; ks < 2; ++ks)
            #pragma unroll
            for (int mi = 0; mi < 4; ++mi)
                areg[pb][ks][mi] =
                    *(const short8*)(Aw + (size_t)mi * 16 * K + k * 64 + ks * 32);
    };

    f32x4 acc[4][4];
    #pragma unroll
    for (int i = 0; i < 4; ++i)
        #pragma unroll
        for (int j = 0; j < 4; ++j) acc[i][j] = (f32x4){0.f, 0.f, 0.f, 0.f};

    // prologue: A(0) -> regs, B(0) -> buf0, B(1) -> buf1
    loadA(0, 0);
    stageB(0, 0);
    stageB(1, 1);
    asm volatile("s_waitcnt vmcnt(4)" ::: "memory");   // A(0)+B(0) landed, B(1) flying
    blockbar();

    #pragma unroll
    for (int k = 0; k < KS; ++k) {
        if (k + 1 < KS) loadA(k + 1, (k + 1) & 1);
        #pragma unroll
        for (int ks = 0; ks < 2; ++ks) {
            short8 bv[4];
            const int cfr = ks * 4 + (l >> 4);
            #pragma unroll
            for (int ni = 0; ni < 4; ++ni) {
                const int row = wc * 64 + ni * 16 + (l & 15);
                bv[ni] = *(const short8*)&lsB[k & 1][row * 64 + ((cfr ^ (row & 7)) << 3)];
            }
            #pragma unroll
            for (int mi = 0; mi < 4; ++mi)
                #pragma unroll
                for (int ni = 0; ni < 4; ++ni)
                    acc[mi][ni] = __builtin_amdgcn_mfma_f32_16x16x32_bf16(
                        areg[k & 1][ks][mi], bv[ni], acc[mi][ni], 0, 0, 0);
        }
        blockbar();                       // all waves done reading buf[k&1]
        if (k + 2 < KS) stageB(k + 2, k & 1);
        if (k + 1 < KS) {
            asm volatile("s_waitcnt vmcnt(4)" ::: "memory");  // B(k+1)+A(k+1) landed
            blockbar();                   // B(k+1) visible to all waves
        }
    }

    // epilogue: C/D layout col = l&15 (n), row = (l>>4)*4 + j (m)
    const int mq = (l >> 4) * 4;
    const int nq = l & 15;
    #pragma unroll
    for (int mi = 0; mi < 4; ++mi) {
        const int mb = m0 + wr * 64 + mi * 16 + mq;
        float mul[4], add[4];
        #pragma unroll
        for (int j = 0; j < 4; ++j) {
            const int m = mb + j;
            if (EPI == 0 || EPI == 1) { mul[j] = 1.f; add[j] = p0[m]; }
            else { const float inv = p0[m] * rsqrtf(p3[m] + EPS_F);
                   mul[j] = inv; add[j] = p1[m] - p2[m] * inv; }
        }
        #pragma unroll
        for (int ni = 0; ni < 4; ++ni) {
            const int n = n0 + wc * 64 + ni * 16 + nq;
            float z[4];
            #pragma unroll
            for (int j = 0; j < 4; ++j) {
                z[j] = acc[mi][ni][j] * mul[j] + add[j];
                if (EPI == 2) z[j] = z[j] / (1.f + __expf(-z[j]));       // SiLU
                if (EPI == 1 || EPI == 3)
                    z[j] += resid[((size_t)b * M + mb + j) * N + n];
            }
            if (EPI == 0 || EPI == 1 || EPI == 2) {
                ushort4v u;
                #pragma unroll
                for (int j = 0; j < 4; ++j) u[j] = f2bf(z[j]);
                *(ushort4v*)&outT[((size_t)b * N + n) * M + mb] = u;     // NHWC bf16
            }
            if (EPI == 1 || EPI == 3) {
                #pragma unroll
                for (int j = 0; j < 4; ++j)
                    outF[((size_t)b * M + mb + j) * N + n] = z[j];       // NCHW f32
            }
        }
    }
}

// ---------------------------------------------------------------------------
// Attention (R7 known-good, 68 us): 4-way channel-split.
// thread = (px 0..15, cg 0..3, di 0..3); wave = di; 16 ch per thread.
// Grid 3200, id&7 = batch -> XCD-local L2 reuse.
// ---------------------------------------------------------------------------
__global__ __launch_bounds__(256, 4)
void attn_k(const short* __restrict__ qkvt,
            const float* __restrict__ fc_w, const float* __restrict__ fc_b,
            const float* __restrict__ ln_g, const float* __restrict__ ln_b,
            short* __restrict__ y2t)
{
    __shared__ short st[4][16][64];   // 8 KB, chunk-swizzled in c

    const int id  = blockIdx.x;
    const int b   = id & 7;
    const int hw0 = (id >> 3) * 16;
    const int t   = threadIdx.x;
    const int px  = t & 15;
    const int cg  = (t >> 4) & 3;
    const int di  = t >> 6;
    const int hw  = hw0 + px;
    const int yy  = hw / 80;
    const int xx  = hw % 80;
    const int r   = 1 << di;

    int   off[9];
    float okf[9];
    #pragma unroll
    for (int jy = 0; jy < 3; ++jy)
        #pragma unroll
        for (int jx = 0; jx < 3; ++jx) {
            const int ny = yy + (jy - 1) * r;
            const int nx = xx + (jx - 1) * r;
            const bool o = (ny >= 0) && (ny < 80) && (nx >= 0) && (nx < 80);
            okf[jy * 3 + jx] = o ? 1.f : 0.f;
            off[jy * 3 + jx] = o ? (ny * 80 + nx) : hw;
        }

    const short* base = qkvt + (size_t)b * 6400 * 768;
    const int ch = di * 64 + cg * 16;

    const short8 qv0 = *(const short8*)(base + (size_t)hw * 768 + ch);
    const short8 qv1 = *(const short8*)(base + (size_t)hw * 768 + ch + 8);
    float qf[16];
    #pragma unroll
    for (int u = 0; u < 8; ++u) { qf[u] = bf2f((unsigned short)qv0[u]);
                                  qf[8 + u] = bf2f((unsigned short)qv1[u]); }

    float s[9];
    #pragma unroll
    for (int j = 0; j < 9; ++j) {
        const short* kp = base + (size_t)off[j] * 768 + 256 + ch;
        const short8 k0 = *(const short8*)kp;
        const short8 k1 = *(const short8*)(kp + 8);
        float a = 0.f;
        #pragma unroll
        for (int u = 0; u < 8; ++u) {
            a = fmaf(qf[u],     bf2f((unsigned short)k0[u]), a);
            a = fmaf(qf[8 + u], bf2f((unsigned short)k1[u]), a);
        }
        s[j] = a;
    }
    #pragma unroll
    for (int j = 0; j < 9; ++j) {
        s[j] += __shfl_xor(s[j], 16, 64);
        s[j] += __shfl_xor(s[j], 32, 64);
        s[j] *= okf[j] * 0.125f;
    }

    float mx = s[0];
    #pragma unroll
    for (int j = 1; j < 9; ++j) mx = fmaxf(mx, s[j]);
    float e[9], sum = 0.f;
    #pragma unroll
    for (int j = 0; j < 9; ++j) { e[j] = __expf(s[j] - mx); sum += e[j]; }
    const float isum = 1.f / sum;
    float pe[9];
    #pragma unroll
    for (int j = 0; j < 9; ++j) pe[j] = e[j] * isum * okf[j];

    float o[16];
    #pragma unroll
    for (int u = 0; u < 16; ++u) o[u] = 0.f;
    #pragma unroll
    for (int j = 0; j < 9; ++j) {
        const short* vp = base + (size_t)off[j] * 768 + 512 + ch;
        const short8 v0 = *(const short8*)vp;
        const short8 v1 = *(const short8*)(vp + 8);
        #pragma unroll
        for (int u = 0; u < 8; ++u) {
            o[u]     = fmaf(pe[j], bf2f((unsigned short)v0[u]), o[u]);
            o[8 + u] = fmaf(pe[j], bf2f((unsigned short)v1[u]), o[8 + u]);
        }
    }
    short8 ov0, ov1;
    #pragma unroll
    for (int u = 0; u < 8; ++u) { ov0[u] = (short)f2bf(o[u]);
                                  ov1[u] = (short)f2bf(o[8 + u]); }
    short* sp = &st[di][px][0];
    *(short8*)(sp + (((cg * 2)     ^ (px & 7)) << 3)) = ov0;
    *(short8*)(sp + (((cg * 2 + 1) ^ (px & 7)) << 3)) = ov1;
    __syncthreads();

    float cw[4];
    #pragma unroll
    for (int s4 = 0; s4 < 4; ++s4) cw[s4] = fc_w[di * 4 + s4] + (s4 == di ? 1.f : 0.f);
    const float fb = fc_b[di];

    const int cc0 = ((cg * 2)     ^ (px & 7)) << 3;
    const int cc1 = ((cg * 2 + 1) ^ (px & 7)) << 3;
    float f[16];
    #pragma unroll
    for (int u = 0; u < 16; ++u) f[u] = fb;
    #pragma unroll
    for (int s4 = 0; s4 < 4; ++s4) {
        const short8 a0 = *(const short8*)(&st[s4][px][0] + cc0);
        const short8 a1 = *(const short8*)(&st[s4][px][0] + cc1);
        #pragma unroll
        for (int u = 0; u < 8; ++u) {
            f[u]     = fmaf(cw[s4], bf2f((unsigned short)a0[u]), f[u]);
            f[8 + u] = fmaf(cw[s4], bf2f((unsigned short)a1[u]), f[8 + u]);
        }
    }
    float mu = 0.f, sq = 0.f;
    #pragma unroll
    for (int u = 0; u < 16; ++u) { mu += f[u]; sq = fmaf(f[u], f[u], sq); }
    mu += __shfl_xor(mu, 16, 64);  mu += __shfl_xor(mu, 32, 64);
    sq += __shfl_xor(sq, 16, 64);  sq += __shfl_xor(sq, 32, 64);
    mu *= (1.f / 64.f);
    const float var  = sq * (1.f / 64.f) - mu * mu;
    const float rstd = rsqrtf(var + EPS_F);

    short* yo = y2t + ((size_t)(b * 6400 + hw)) * 256 + ch;
    short8 y0, y1;
    #pragma unroll
    for (int u = 0; u < 8; ++u) {
        const int c0 = cg * 16 + u, c1 = cg * 16 + 8 + u;
        y0[u] = (short)f2bf((f[u]     - mu) * rstd * ln_g[c0] + ln_b[c0]);
        y1[u] = (short)f2bf((f[8 + u] - mu) * rstd * ln_g[c1] + ln_b[c1]);
    }
    *(short8*)yo       = y0;
    *(short8*)(yo + 8) = y1;
}

// ---------------------------------------------------------------------------
// x NCHW f32 -> xt NHWC bf16
// ---------------------------------------------------------------------------
__global__ void xt_k(const float* __restrict__ x, short* __restrict__ xt)
{
    const int b  = blockIdx.y;
    const int hw = blockIdx.x * 256 + threadIdx.x;
    const float* xb = x + (size_t)b * 256 * 6400 + hw;
    short* o = xt + ((size_t)b * 6400 + hw) * 256;
    #pragma unroll 4
    for (int c8 = 0; c8 < 32; ++c8) {
        short8 v;
        #pragma unroll
        for (int u = 0; u < 8; ++u)
            v[u] = (short)f2bf(xb[(size_t)(c8 * 8 + u) * 6400]);
        *(short8*)&o[c8 * 8] = v;
    }
}

// ---------------------------------------------------------------------------
// fp32 -> bf16 weight conversion (qkv_w | proj_w | w1 | w2 concatenated)
// ---------------------------------------------------------------------------
__global__ void wc_k(const float* __restrict__ a, const float* __restrict__ bb,
                     const float* __restrict__ c, const float* __restrict__ d,
                     short* __restrict__ o)
{
    const int i = blockIdx.x * 256 + threadIdx.x;
    float v;
    if      (i < 196608)  v = a[i];
    else if (i < 262144)  v = bb[i - 196608];
    else if (i < 393216)  v = c[i - 262144];
    else                  v = d[i - 393216];
    o[i] = (short)f2bf(v);
}

// ---------------------------------------------------------------------------
extern "C" void kernel_launch(void* const* d_in, const int* in_sizes, int n_in,
                              void* d_out, int out_size, void* d_ws, size_t ws_size,
                              hipStream_t stream)
{
    const float* x      = (const float*)d_in[0];
    const float* qkv_w  = (const float*)d_in[1];
    const float* qkv_b  = (const float*)d_in[2];
    const float* fc_w   = (const float*)d_in[3];
    const float* fc_b   = (const float*)d_in[4];
    const float* ln_g   = (const float*)d_in[5];
    const float* ln_b   = (const float*)d_in[6];
    const float* proj_w = (const float*)d_in[7];
    const float* proj_b = (const float*)d_in[8];
    const float* w1     = (const float*)d_in[9];
    const float* bn1_g  = (const float*)d_in[10];
    const float* bn1_b  = (const float*)d_in[11];
    const float* bn1_m  = (const float*)d_in[12];
    const float* bn1_v  = (const float*)d_in[13];
    const float* w2     = (const float*)d_in[14];
    const float* bn2_g  = (const float*)d_in[15];
    const float* bn2_b  = (const float*)d_in[16];
    const float* bn2_m  = (const float*)d_in[17];
    const float* bn2_v  = (const float*)d_in[18];
    float* out = (float*)d_out;

    const int B = 8;

    char* ws = (char*)d_ws;
    short* wqkvb  = (short*)(ws + 0);                   // 196608 bf16
    short* wprojb = wqkvb + 196608;                     //  65536
    short* w1b    = wprojb + 65536;                     // 131072
    short* w2b    = w1b + 131072;                       // 131072
    short* xt     = (short*)(ws + 1048576);             // [B][HW][256]
    short* qkvt   = (short*)(ws + 27262976);            // [B][HW][768]; later h
    short* y2t    = (short*)(ws + 105906176);           // [B][HW][256]
    short* x1t    = (short*)(ws + 132120576);           // [B][HW][256]
    float* x1f    = (float*)(ws + 158334976);           // [B][256][HW] f32
    short* h      = qkvt;

    dim3 blk(256);

    // 0) weights -> bf16
    wc_k<<<dim3(2048), blk, 0, stream>>>(qkv_w, proj_w, w1, w2, wqkvb);

    // 1) x -> NHWC bf16
    xt_k<<<dim3(25, B), blk, 0, stream>>>(x, xt);

    // 2) qkv GEMM: M=768 K=256 -> qkvt NHWC (+bias)
    ga_k<0, 4><<<dim3(50 * 6 * 8), blk, 0, stream>>>(
        wqkvb, xt, 768, qkv_b, nullptr, nullptr, nullptr, nullptr,
        qkvt, nullptr);

    // 3) attention + fc-mix + LN -> y2t NHWC
    attn_k<<<dim3(3200), blk, 0, stream>>>(qkvt, fc_w, fc_b, ln_g, ln_b, y2t);

    // 4) proj GEMM: M=256 K=256, +bias +x -> x1t (bf16 NHWC) + x1f (f32 NCHW)
    ga_k<1, 4><<<dim3(50 * 2 * 8), blk, 0, stream>>>(
        wprojb, y2t, 256, proj_b, nullptr, nullptr, nullptr, x,
        x1t, x1f);

    // 5) mlp1: M=512 K=256, BN1+SiLU -> h NHWC bf16
    ga_k<2, 4><<<dim3(50 * 4 * 8), blk, 0, stream>>>(
        w1b, x1t, 512, bn1_g, bn1_b, bn1_m, bn1_v, nullptr,
        h, nullptr);

    // 6) mlp2: M=256 K=512, BN2 + x1 resid -> out f32 NCHW
    ga_k<3, 8><<<dim3(50 * 2 * 8), blk, 0, stream>>>(
        w2b, h, 256, bn2_g, bn2_b, bn2_m, bn2_v, x1f,
        nullptr, out);
}

// Round 10
// 375.077 us; speedup vs baseline: 1.0951x; 1.0951x over previous
//
#include <hip/hip_runtime.h>

#define EPS_F 1e-5f

typedef __attribute__((ext_vector_type(8))) short short8;
typedef __attribute__((ext_vector_type(4))) float f32x4;
typedef __attribute__((ext_vector_type(4))) unsigned short ushort4v;
typedef __attribute__((address_space(1))) void gvoid;
typedef __attribute__((address_space(3))) void svoid;

__device__ __forceinline__ float bf2f(unsigned short u){
    union { unsigned int i; float f; } v; v.i = ((unsigned int)u) << 16; return v.f;
}
__device__ __forceinline__ unsigned short f2bf(float f){
    union { float f; unsigned int i; } v; v.f = f;
    unsigned int r = v.i + 0x7FFFu + ((v.i >> 16) & 1u);
    return (unsigned short)(r >> 16);
}

// ---------------------------------------------------------------------------
// bf16 MFMA GEMM v3 (2-phase, T3-minimum): C[m][n] = sum_k A[m][k]*Act[n][k]
// BK=32, A+B double-buffered in 32 KB total -> 3 blocks/CU kept.
// Loop: {stage(k+1) issue; compute(k); __syncthreads()} - ONE barrier/step,
// stage latency hidden under 16 MFMA + 8 ds_read.
// LDS swizzle: 4-chunk rows, chunk ^= (row&3)  (2-way conflicts only = free).
// Flat grid, XCD swizzle: id&7 = batch, id>>3 = n-tile + 50*m-tile.
// EPI 0: +bias              -> outT NHWC bf16            (qkv)
// EPI 1: +bias +resid(NCHW) -> outT NHWC bf16 + outF f32 (proj -> x1)
// EPI 2: BN+SiLU            -> outT NHWC bf16            (mlp1)
// EPI 3: BN+resid(NCHW)     -> outF f32 NCHW             (mlp2 -> out)
// KS = K/32.
// ---------------------------------------------------------------------------
template<int EPI, int KS>
__global__ __launch_bounds__(256, 3)
void mm2_k(const short* __restrict__ A, const short* __restrict__ Bt,
           const int M,
           const float* __restrict__ p0, const float* __restrict__ p1,
           const float* __restrict__ p2, const float* __restrict__ p3,
           const float* __restrict__ resid,
           short* __restrict__ outT, float* __restrict__ outF)
{
    const int N = 6400;
    const int K = KS * 32;
    __shared__ short lsA[2][128 * 32];   // 2 x 8 KB
    __shared__ short lsB[2][128 * 32];   // 2 x 8 KB

    const int id = blockIdx.x;
    const int b  = id & 7;               // batch -> XCD
    const int rr = id >> 3;
    const int n0 = (rr % 50) * 128;
    const int m0 = (rr / 50) * 128;
    const int t  = threadIdx.x;
    const int l  = t & 63;
    const int w  = t >> 6;
    const int wr = w >> 1, wc = w & 1;

    const short* Bb = Bt + (size_t)b * N * K;

    // staging map: linear short off = t*8 + q*2048 -> row = t/4 + q*64,
    // chunk-in-row = t&3; global src chunk pre-swizzled by ^(row&3).
    const int srow = t >> 2;
    const int schk = t & 3;

    auto stage = [&](int k, int bufi) {
        #pragma unroll
        for (int q = 0; q < 2; ++q) {
            const int row = srow + q * 64;
            const int cs  = schk ^ (row & 3);
            const short* ga = A  + (size_t)(m0 + row) * K + k * 32 + (cs << 3);
            __builtin_amdgcn_global_load_lds((gvoid*)ga,
                (svoid*)(&lsA[bufi][t * 8 + q * 2048]), 16, 0, 0);
            const short* gb = Bb + (size_t)(n0 + row) * K + k * 32 + (cs << 3);
            __builtin_amdgcn_global_load_lds((gvoid*)gb,
                (svoid*)(&lsB[bufi][t * 8 + q * 2048]), 16, 0, 0);
        }
    };

    f32x4 acc[4][4];
    #pragma unroll
    for (int i = 0; i < 4; ++i)
        #pragma unroll
        for (int j = 0; j < 4; ++j) acc[i][j] = (f32x4){0.f, 0.f, 0.f, 0.f};

    stage(0, 0);
    __syncthreads();                     // buf0 ready (compiler drains vmcnt)

    #pragma unroll
    for (int k = 0; k < KS; ++k) {
        if (k + 1 < KS) stage(k + 1, (k + 1) & 1);   // issue before compute
        {
            short8 av[4], bv[4];
            const int cfr = l >> 4;                  // my k-chunk 0..3
            #pragma unroll
            for (int mi = 0; mi < 4; ++mi) {
                const int row = wr * 64 + mi * 16 + (l & 15);
                av[mi] = *(const short8*)&lsA[k & 1][row * 32 + ((cfr ^ (row & 3)) << 3)];
            }
            #pragma unroll
            for (int ni = 0; ni < 4; ++ni) {
                const int row = wc * 64 + ni * 16 + (l & 15);
                bv[ni] = *(const short8*)&lsB[k & 1][row * 32 + ((cfr ^ (row & 3)) << 3)];
            }
            #pragma unroll
            for (int mi = 0; mi < 4; ++mi)
                #pragma unroll
                for (int ni = 0; ni < 4; ++ni)
                    acc[mi][ni] = __builtin_amdgcn_mfma_f32_16x16x32_bf16(
                        av[mi], bv[ni], acc[mi][ni], 0, 0, 0);
        }
        __syncthreads();                 // stage(k+1) landed; buf[k&1] reads done
    }

    // epilogue: C/D layout col = l&15 (n), row = (l>>4)*4 + j (m)
    const int mq = (l >> 4) * 4;
    const int nq = l & 15;
    #pragma unroll
    for (int mi = 0; mi < 4; ++mi) {
        const int mb = m0 + wr * 64 + mi * 16 + mq;
        float mul[4], add[4];
        #pragma unroll
        for (int j = 0; j < 4; ++j) {
            const int m = mb + j;
            if (EPI == 0 || EPI == 1) { mul[j] = 1.f; add[j] = p0[m]; }
            else { const float inv = p0[m] * rsqrtf(p3[m] + EPS_F);
                   mul[j] = inv; add[j] = p1[m] - p2[m] * inv; }
        }
        #pragma unroll
        for (int ni = 0; ni < 4; ++ni) {
            const int n = n0 + wc * 64 + ni * 16 + nq;
            float z[4];
            #pragma unroll
            for (int j = 0; j < 4; ++j) {
                z[j] = acc[mi][ni][j] * mul[j] + add[j];
                if (EPI == 2) z[j] = z[j] / (1.f + __expf(-z[j]));       // SiLU
                if (EPI == 1 || EPI == 3)
                    z[j] += resid[((size_t)b * M + mb + j) * N + n];
            }
            if (EPI == 0 || EPI == 1 || EPI == 2) {
                ushort4v u;
                #pragma unroll
                for (int j = 0; j < 4; ++j) u[j] = f2bf(z[j]);
                *(ushort4v*)&outT[((size_t)b * N + n) * M + mb] = u;     // NHWC bf16
            }
            if (EPI == 1 || EPI == 3) {
                #pragma unroll
                for (int j = 0; j < 4; ++j)
                    outF[((size_t)b * M + mb + j) * N + n] = z[j];       // NCHW f32
            }
        }
    }
}

// ---------------------------------------------------------------------------
// Attention (R7 known-good, 67 us): 4-way channel-split.
// thread = (px 0..15, cg 0..3, di 0..3); wave = di; 16 ch per thread.
// Grid 3200, id&7 = batch -> XCD-local L2 reuse.
// ---------------------------------------------------------------------------
__global__ __launch_bounds__(256, 4)
void attn_k(const short* __restrict__ qkvt,
            const float* __restrict__ fc_w, const float* __restrict__ fc_b,
            const float* __restrict__ ln_g, const float* __restrict__ ln_b,
            short* __restrict__ y2t)
{
    __shared__ short st[4][16][64];   // 8 KB, chunk-swizzled in c

    const int id  = blockIdx.x;
    const int b   = id & 7;
    const int hw0 = (id >> 3) * 16;
    const int t   = threadIdx.x;
    const int px  = t & 15;
    const int cg  = (t >> 4) & 3;
    const int di  = t >> 6;
    const int hw  = hw0 + px;
    const int yy  = hw / 80;
    const int xx  = hw % 80;
    const int r   = 1 << di;

    int   off[9];
    float okf[9];
    #pragma unroll
    for (int jy = 0; jy < 3; ++jy)
        #pragma unroll
        for (int jx = 0; jx < 3; ++jx) {
            const int ny = yy + (jy - 1) * r;
            const int nx = xx + (jx - 1) * r;
            const bool o = (ny >= 0) && (ny < 80) && (nx >= 0) && (nx < 80);
            okf[jy * 3 + jx] = o ? 1.f : 0.f;
            off[jy * 3 + jx] = o ? (ny * 80 + nx) : hw;
        }

    const short* base = qkvt + (size_t)b * 6400 * 768;
    const int ch = di * 64 + cg * 16;

    const short8 qv0 = *(const short8*)(base + (size_t)hw * 768 + ch);
    const short8 qv1 = *(const short8*)(base + (size_t)hw * 768 + ch + 8);
    float qf[16];
    #pragma unroll
    for (int u = 0; u < 8; ++u) { qf[u] = bf2f((unsigned short)qv0[u]);
                                  qf[8 + u] = bf2f((unsigned short)qv1[u]); }

    float s[9];
    #pragma unroll
    for (int j = 0; j < 9; ++j) {
        const short* kp = base + (size_t)off[j] * 768 + 256 + ch;
        const short8 k0 = *(const short8*)kp;
        const short8 k1 = *(const short8*)(kp + 8);
        float a = 0.f;
        #pragma unroll
        for (int u = 0; u < 8; ++u) {
            a = fmaf(qf[u],     bf2f((unsigned short)k0[u]), a);
            a = fmaf(qf[8 + u], bf2f((unsigned short)k1[u]), a);
        }
        s[j] = a;
    }
    #pragma unroll
    for (int j = 0; j < 9; ++j) {
        s[j] += __shfl_xor(s[j], 16, 64);
        s[j] += __shfl_xor(s[j], 32, 64);
        s[j] *= okf[j] * 0.125f;
    }

    float mx = s[0];
    #pragma unroll
    for (int j = 1; j < 9; ++j) mx = fmaxf(mx, s[j]);
    float e[9], sum = 0.f;
    #pragma unroll
    for (int j = 0; j < 9; ++j) { e[j] = __expf(s[j] - mx); sum += e[j]; }
    const float isum = 1.f / sum;
    float pe[9];
    #pragma unroll
    for (int j = 0; j < 9; ++j) pe[j] = e[j] * isum * okf[j];

    float o[16];
    #pragma unroll
    for (int u = 0; u < 16; ++u) o[u] = 0.f;
    #pragma unroll
    for (int j = 0; j < 9; ++j) {
        const short* vp = base + (size_t)off[j] * 768 + 512 + ch;
        const short8 v0 = *(const short8*)vp;
        const short8 v1 = *(const short8*)(vp + 8);
        #pragma unroll
        for (int u = 0; u < 8; ++u) {
            o[u]     = fmaf(pe[j], bf2f((unsigned short)v0[u]), o[u]);
            o[8 + u] = fmaf(pe[j], bf2f((unsigned short)v1[u]), o[8 + u]);
        }
    }
    short8 ov0, ov1;
    #pragma unroll
    for (int u = 0; u < 8; ++u) { ov0[u] = (short)f2bf(o[u]);
                                  ov1[u] = (short)f2bf(o[8 + u]); }
    short* sp = &st[di][px][0];
    *(short8*)(sp + (((cg * 2)     ^ (px & 7)) << 3)) = ov0;
    *(short8*)(sp + (((cg * 2 + 1) ^ (px & 7)) << 3)) = ov1;
    __syncthreads();

    float cw[4];
    #pragma unroll
    for (int s4 = 0; s4 < 4; ++s4) cw[s4] = fc_w[di * 4 + s4] + (s4 == di ? 1.f : 0.f);
    const float fb = fc_b[di];

    const int cc0 = ((cg * 2)     ^ (px & 7)) << 3;
    const int cc1 = ((cg * 2 + 1) ^ (px & 7)) << 3;
    float f[16];
    #pragma unroll
    for (int u = 0; u < 16; ++u) f[u] = fb;
    #pragma unroll
    for (int s4 = 0; s4 < 4; ++s4) {
        const short8 a0 = *(const short8*)(&st[s4][px][0] + cc0);
        const short8 a1 = *(const short8*)(&st[s4][px][0] + cc1);
        #pragma unroll
        for (int u = 0; u < 8; ++u) {
            f[u]     = fmaf(cw[s4], bf2f((unsigned short)a0[u]), f[u]);
            f[8 + u] = fmaf(cw[s4], bf2f((unsigned short)a1[u]), f[8 + u]);
        }
    }
    float mu = 0.f, sq = 0.f;
    #pragma unroll
    for (int u = 0; u < 16; ++u) { mu += f[u]; sq = fmaf(f[u], f[u], sq); }
    mu += __shfl_xor(mu, 16, 64);  mu += __shfl_xor(mu, 32, 64);
    sq += __shfl_xor(sq, 16, 64);  sq += __shfl_xor(sq, 32, 64);
    mu *= (1.f / 64.f);
    const float var  = sq * (1.f / 64.f) - mu * mu;
    const float rstd = rsqrtf(var + EPS_F);

    short* yo = y2t + ((size_t)(b * 6400 + hw)) * 256 + ch;
    short8 y0, y1;
    #pragma unroll
    for (int u = 0; u < 8; ++u) {
        const int c0 = cg * 16 + u, c1 = cg * 16 + 8 + u;
        y0[u] = (short)f2bf((f[u]     - mu) * rstd * ln_g[c0] + ln_b[c0]);
        y1[u] = (short)f2bf((f[8 + u] - mu) * rstd * ln_g[c1] + ln_b[c1]);
    }
    *(short8*)yo       = y0;
    *(short8*)(yo + 8) = y1;
}

// ---------------------------------------------------------------------------
// x NCHW f32 -> xt NHWC bf16
// ---------------------------------------------------------------------------
__global__ void xt_k(const float* __restrict__ x, short* __restrict__ xt)
{
    const int b  = blockIdx.y;
    const int hw = blockIdx.x * 256 + threadIdx.x;
    const float* xb = x + (size_t)b * 256 * 6400 + hw;
    short* o = xt + ((size_t)b * 6400 + hw) * 256;
    #pragma unroll 4
    for (int c8 = 0; c8 < 32; ++c8) {
        short8 v;
        #pragma unroll
        for (int u = 0; u < 8; ++u)
            v[u] = (short)f2bf(xb[(size_t)(c8 * 8 + u) * 6400]);
        *(short8*)&o[c8 * 8] = v;
    }
}

// ---------------------------------------------------------------------------
// fp32 -> bf16 weight conversion (qkv_w | proj_w | w1 | w2 concatenated)
// ---------------------------------------------------------------------------
__global__ void wc_k(const float* __restrict__ a, const float* __restrict__ bb,
                     const float* __restrict__ c, const float* __restrict__ d,
                     short* __restrict__ o)
{
    const int i = blockIdx.x * 256 + threadIdx.x;
    float v;
    if      (i < 196608)  v = a[i];
    else if (i < 262144)  v = bb[i - 196608];
    else if (i < 393216)  v = c[i - 262144];
    else                  v = d[i - 393216];
    o[i] = (short)f2bf(v);
}

// ---------------------------------------------------------------------------
extern "C" void kernel_launch(void* const* d_in, const int* in_sizes, int n_in,
                              void* d_out, int out_size, void* d_ws, size_t ws_size,
                              hipStream_t stream)
{
    const float* x      = (const float*)d_in[0];
    const float* qkv_w  = (const float*)d_in[1];
    const float* qkv_b  = (const float*)d_in[2];
    const float* fc_w   = (const float*)d_in[3];
    const float* fc_b   = (const float*)d_in[4];
    const float* ln_g   = (const float*)d_in[5];
    const float* ln_b   = (const float*)d_in[6];
    const float* proj_w = (const float*)d_in[7];
    const float* proj_b = (const float*)d_in[8];
    const float* w1     = (const float*)d_in[9];
    const float* bn1_g  = (const float*)d_in[10];
    const float* bn1_b  = (const float*)d_in[11];
    const float* bn1_m  = (const float*)d_in[12];
    const float* bn1_v  = (const float*)d_in[13];
    const float* w2     = (const float*)d_in[14];
    const float* bn2_g  = (const float*)d_in[15];
    const float* bn2_b  = (const float*)d_in[16];
    const float* bn2_m  = (const float*)d_in[17];
    const float* bn2_v  = (const float*)d_in[18];
    float* out = (float*)d_out;

    const int B = 8;

    char* ws = (char*)d_ws;
    short* wqkvb  = (short*)(ws + 0);                   // 196608 bf16
    short* wprojb = wqkvb + 196608;                     //  65536
    short* w1b    = wprojb + 65536;                     // 131072
    short* w2b    = w1b + 131072;                       // 131072
    short* xt     = (short*)(ws + 1048576);             // [B][HW][256]
    short* qkvt   = (short*)(ws + 27262976);            // [B][HW][768]; later h
    short* y2t    = (short*)(ws + 105906176);           // [B][HW][256]
    short* x1t    = (short*)(ws + 132120576);           // [B][HW][256]
    float* x1f    = (float*)(ws + 158334976);           // [B][256][HW] f32
    short* h      = qkvt;

    dim3 blk(256);

    // 0) weights -> bf16
    wc_k<<<dim3(2048), blk, 0, stream>>>(qkv_w, proj_w, w1, w2, wqkvb);

    // 1) x -> NHWC bf16
    xt_k<<<dim3(25, B), blk, 0, stream>>>(x, xt);

    // 2) qkv GEMM: M=768 K=256 -> qkvt NHWC (+bias)
    mm2_k<0, 8><<<dim3(50 * 6 * 8), blk, 0, stream>>>(
        wqkvb, xt, 768, qkv_b, nullptr, nullptr, nullptr, nullptr,
        qkvt, nullptr);

    // 3) attention + fc-mix + LN -> y2t NHWC
    attn_k<<<dim3(3200), blk, 0, stream>>>(qkvt, fc_w, fc_b, ln_g, ln_b, y2t);

    // 4) proj GEMM: M=256 K=256, +bias +x -> x1t (bf16 NHWC) + x1f (f32 NCHW)
    mm2_k<1, 8><<<dim3(50 * 2 * 8), blk, 0, stream>>>(
        wprojb, y2t, 256, proj_b, nullptr, nullptr, nullptr, x,
        x1t, x1f);

    // 5) mlp1: M=512 K=256, BN1+SiLU -> h NHWC bf16
    mm2_k<2, 8><<<dim3(50 * 4 * 8), blk, 0, stream>>>(
        w1b, x1t, 512, bn1_g, bn1_b, bn1_m, bn1_v, nullptr,
        h, nullptr);

    // 6) mlp2: M=256 K=512, BN2 + x1 resid -> out f32 NCHW
    mm2_k<3, 16><<<dim3(50 * 2 * 8), blk, 0, stream>>>(
        w2b, h, 256, bn2_g, bn2_b, bn2_m, bn2_v, x1f,
        nullptr, out);
}